// Round 3
// baseline (2754.911 us; speedup 1.0000x reference)
//
#include <hip/hip_runtime.h>
#include <stdint.h>
#include <stddef.h>

// Problem dims
#define B_  128
#define S_  48
#define E_  620
#define EP  640    // E padded to multiple of 32 (zeros)
#define H_  2400
#define N3  7200   // 3*H (r,i,n concatenated)
#define KH  2400
#define KA  7200   // logical K for recurrent GEMM: [h_hi | h_lo | h_hi]
#define ZSPLIT 6
#define KCHUNK 1216  // 38*32; 6*1216 = 7296 >= 7200

typedef __attribute__((ext_vector_type(8))) short   short8;
typedef __attribute__((ext_vector_type(8))) __bf16  bf16x8;
typedef __attribute__((ext_vector_type(4))) float   floatx4;

__device__ __forceinline__ short f2bf(float f) {
  union { float f; uint32_t u; } v; v.f = f;
  return (short)((v.u + 0x7fffu + ((v.u >> 16) & 1u)) >> 16);  // RNE
}
__device__ __forceinline__ float bf2f(short s) {
  union { uint32_t u; float f; } v; v.u = ((uint32_t)(uint16_t)s) << 16;
  return v.f;
}

// async 16B global->LDS (dest = wave-uniform base + lane*16)
__device__ __forceinline__ void gld16(const short* g, short* l) {
  __builtin_amdgcn_global_load_lds(
      (const __attribute__((address_space(1))) void*)g,
      (__attribute__((address_space(3))) void*)l, 16, 0, 0);
}

// ---- x = bf16(emb[tokens]), padded [6144, 640] ----
__global__ void gather_cast_x(const int* __restrict__ tokens,
                              const float* __restrict__ emb,
                              short* __restrict__ xb) {
  int idx = blockIdx.x * 256 + threadIdx.x;       // over 6144*EP
  int m = idx / EP, c = idx - m * EP;
  float v = 0.f;
  if (c < E_) v = emb[(size_t)tokens[m] * E_ + c];
  xb[idx] = f2bf(v);
}

// ---- W_i = bf16 concat(W_ir,W_ii,W_in) [7200, 640]; bias concat [7200] ----
__global__ void convert_wi(const float* __restrict__ Wir, const float* __restrict__ Wii,
                           const float* __restrict__ Win,
                           const float* __restrict__ bir, const float* __restrict__ bii,
                           const float* __restrict__ bin,
                           short* __restrict__ Wi, float* __restrict__ bias) {
  int idx = blockIdx.x * 256 + threadIdx.x;       // over N3*EP
  int r = idx / EP, c = idx - r * EP;
  const float* W = (r < H_) ? Wir : (r < 2*H_ ? Wii : Win);
  int rr = (r < H_) ? r : (r < 2*H_ ? r - H_ : r - 2*H_);
  float v = (c < E_) ? W[(size_t)rr * E_ + c] : 0.f;
  Wi[idx] = f2bf(v);
  if (c == 0) {
    const float* bb = (r < H_) ? bir : (r < 2*H_ ? bii : bin);
    bias[r] = bb[rr];
  }
}

// ---- W2 = [W_hi | W_lo] of concat(W_hr,W_hi,W_hn): [7200, 4800] bf16 ----
__global__ void convert_wh(const float* __restrict__ Whr, const float* __restrict__ Whi,
                           const float* __restrict__ Whn, short* __restrict__ W2) {
  int idx = blockIdx.x * 256 + threadIdx.x;       // over N3*KH
  int r = idx / KH, c = idx - r * KH;
  const float* W = (r < H_) ? Whr : (r < 2*H_ ? Whi : Whn);
  int rr = (r < H_) ? r : (r < 2*H_ ? r - H_ : r - 2*H_);
  float w = W[(size_t)rr * KH + c];
  short hi = f2bf(w);
  short lo = f2bf(w - bf2f(hi));
  W2[(size_t)r * 4800 + c] = hi;
  W2[(size_t)r * 4800 + KH + c] = lo;
}

__global__ void init_h(float* __restrict__ h, short* __restrict__ hb) {
  int idx = blockIdx.x * 256 + threadIdx.x;       // over B_*KA
  hb[idx] = 0;
  if (idx < B_ * H_) h[idx] = 0.f;
}

// ---- Generic NT bf16 GEMM: C[m,n] = sum_k A[m,k]*B[n,k] (+bias[n]) ----
// Tile 128x128xBK32, 256 threads = 4 waves, 64x64 per wave via 16x16x32 MFMA.
// Fragment-major LDS: 16B chunk index c = mtile*64 + q*16 + fm, so a wave's
// ds_read_b128 is base + mtile*1024 + lane*16 (conflict-free), and staging is
// global_load_lds width-16 with chunk = tid ordering (dest = base + lane*16).
// grid.z = K-split (kchunk); f32 partials to Cf + z*czstride, OR bf16 to Cb.
// bkwrap: B's k-index = (k < bkwrap ? k : k - bkwrap) -> realizes
// B' = [W_hi | W_hi | W_lo] over stored [W_hi | W_lo].
__global__ __launch_bounds__(256) void gemm_nt(
    const short* __restrict__ A, int lda,
    const short* __restrict__ Bm, int ldb, int N,
    float* __restrict__ Cf, short* __restrict__ Cb, int ldc, long czstride,
    const float* __restrict__ bias, int K, int kchunk, int bkwrap)
{
  __shared__ short As[4096];   // 512 chunks of 16B (128 rows x 32 k)
  __shared__ short Bs[4096];

  const int tid = threadIdx.x;
  const int m0 = blockIdx.x * 128;
  const int n0 = blockIdx.y * 128;
  const int z  = blockIdx.z;
  const int kb = z * kchunk;
  const int ke = min(K, kb + kchunk);

  const int lane = tid & 63;
  const int w  = tid >> 6;
  const int wm = (w >> 1) * 64;
  const int wn = (w & 1) * 64;

  // staging descriptors: chunks c0 = tid, c1 = tid + 256
  // chunk c -> row = (c>>6)*16 + (c&15), kcol = ((c>>4)&3)*8
  const int c0 = tid, c1 = tid + 256;
  const int rA0 = m0 + (c0 >> 6) * 16 + (c0 & 15), q0 = ((c0 >> 4) & 3) * 8;
  const int rA1 = m0 + (c1 >> 6) * 16 + (c1 & 15), q1 = ((c1 >> 4) & 3) * 8;
  int rB0 = n0 + (c0 >> 6) * 16 + (c0 & 15); if (rB0 >= N) rB0 = N - 1;
  int rB1 = n0 + (c1 >> 6) * 16 + (c1 & 15); if (rB1 >= N) rB1 = N - 1;

  floatx4 acc[4][4] = {};

  for (int k0 = kb; k0 < ke; k0 += 32) {
    const int bk0 = (k0 < bkwrap) ? k0 : k0 - bkwrap;
    gld16(A  + (size_t)rA0 * lda + k0  + q0, As + c0 * 8);
    gld16(A  + (size_t)rA1 * lda + k0  + q1, As + c1 * 8);
    gld16(Bm + (size_t)rB0 * ldb + bk0 + q0, Bs + c0 * 8);
    gld16(Bm + (size_t)rB1 * ldb + bk0 + q1, Bs + c1 * 8);
    __syncthreads();   // drains vmcnt -> LDS visible

    bf16x8 a[4], b[4];
    const short* aP = As + ((wm >> 4) * 64 + lane) * 8;
    const short* bP = Bs + ((wn >> 4) * 64 + lane) * 8;
    #pragma unroll
    for (int i = 0; i < 4; ++i) {
      a[i] = __builtin_bit_cast(bf16x8, *(const short8*)(aP + i * 512));
      b[i] = __builtin_bit_cast(bf16x8, *(const short8*)(bP + i * 512));
    }
    #pragma unroll
    for (int mf = 0; mf < 4; ++mf)
      #pragma unroll
      for (int nf = 0; nf < 4; ++nf)
        acc[mf][nf] = __builtin_amdgcn_mfma_f32_16x16x32_bf16(
            a[mf], b[nf], acc[mf][nf], 0, 0, 0);
    __syncthreads();
  }

  // C/D layout (m89-verified): col = lane&15, row = (lane>>4)*4 + reg
  const int col = lane & 15;
  const int qr = (lane >> 4) * 4;
  #pragma unroll
  for (int nf = 0; nf < 4; ++nf) {
    int n = n0 + wn + nf * 16 + col;
    if (n >= N) continue;
    float bv = bias ? bias[n] : 0.f;
    #pragma unroll
    for (int mf = 0; mf < 4; ++mf) {
      #pragma unroll
      for (int r = 0; r < 4; ++r) {
        int m = m0 + wm + mf * 16 + qr + r;
        float v = acc[mf][nf][r] + bv;
        if (Cf) Cf[(size_t)z * czstride + (size_t)m * ldc + n] = v;
        else    Cb[(size_t)m * ldc + n] = f2bf(v);
      }
    }
  }
}

// ---- GRU gate update for step t; h kept f32, A' = [h_hi|h_lo|h_hi] bf16 ----
__global__ void gate_step(const float* __restrict__ Gp, const short* __restrict__ gx,
                          float* __restrict__ h, short* __restrict__ hb,
                          const int* __restrict__ lengths, float* __restrict__ out,
                          int t)
{
  int idx = blockIdx.x * 256 + threadIdx.x;   // over B_*H_
  int b = idx / H_;
  int j = idx - b * H_;

  size_t rx = ((size_t)b * S_ + t) * N3;
  float xr = bf2f(gx[rx + j]);
  float xi = bf2f(gx[rx + H_ + j]);
  float xn = bf2f(gx[rx + 2 * H_ + j]);

  size_t gi = (size_t)b * N3;
  float Gr = 0.f, Gi = 0.f, Gn = 0.f;
  #pragma unroll
  for (int z = 0; z < ZSPLIT; ++z) {
    const float* Gz = Gp + (size_t)z * B_ * N3 + gi;
    Gr += Gz[j]; Gi += Gz[H_ + j]; Gn += Gz[2 * H_ + j];
  }

  float ho = h[idx];
  float r  = 1.f / (1.f + __expf(-(xr + Gr)));
  float ig = 1.f / (1.f + __expf(-(xi + Gi)));
  float n  = tanhf(xn + r * Gn);
  float hn = (1.f - ig) * n + ig * ho;

  h[idx] = hn;
  short hi16 = f2bf(hn);
  short lo16 = f2bf(hn - bf2f(hi16));
  size_t ra = (size_t)b * KA;
  hb[ra + j]            = hi16;
  hb[ra + H_ + j]       = lo16;
  hb[ra + 2 * H_ + j]   = hi16;

  int lc = lengths[b] - 1;
  lc = lc < 0 ? 0 : (lc > S_ - 1 ? S_ - 1 : lc);
  if (t == lc) out[idx] = hn;
}

extern "C" void kernel_launch(void* const* d_in, const int* in_sizes, int n_in,
                              void* d_out, int out_size, void* d_ws, size_t ws_size,
                              hipStream_t stream)
{
  const int*   tokens  = (const int*)d_in[0];
  const int*   lengths = (const int*)d_in[1];
  const float* emb = (const float*)d_in[2];
  const float* Wir = (const float*)d_in[3];
  const float* Wii = (const float*)d_in[4];
  const float* Win = (const float*)d_in[5];
  const float* bir = (const float*)d_in[6];
  const float* bii = (const float*)d_in[7];
  const float* bin = (const float*)d_in[8];
  const float* Whr = (const float*)d_in[9];
  const float* Whi = (const float*)d_in[10];
  const float* Whn = (const float*)d_in[11];
  float* out = (float*)d_out;

  char* ws = (char*)d_ws;
  size_t off = 0;
  auto alloc = [&](size_t bytes) {
    void* p = ws + off;
    off = (off + bytes + 255) & ~(size_t)255;
    return p;
  };
  short* xb   = (short*)alloc((size_t)(B_ * S_) * EP * 2);     //  7.9 MB
  short* Wi   = (short*)alloc((size_t)N3 * EP * 2);            //  9.2 MB
  short* W2   = (short*)alloc((size_t)N3 * 4800 * 2);          // 69.1 MB [W_hi|W_lo]
  float* bias = (float*)alloc((size_t)N3 * 4);
  short* gx   = (short*)alloc((size_t)(B_ * S_) * N3 * 2);     // 88.5 MB
  float* Gp   = (float*)alloc((size_t)ZSPLIT * B_ * N3 * 4);   // 22.1 MB
  float* h    = (float*)alloc((size_t)B_ * H_ * 4);
  short* hb   = (short*)alloc((size_t)B_ * KA * 2);            //  1.8 MB

  // conversions / gather (independent, cheap)
  gather_cast_x<<<(B_ * S_ * EP) / 256, 256, 0, stream>>>(tokens, emb, xb);
  convert_wi<<<(N3 * EP) / 256, 256, 0, stream>>>(Wir, Wii, Win, bir, bii, bin, Wi, bias);
  convert_wh<<<(N3 * KH) / 256, 256, 0, stream>>>(Whr, Whi, Whn, W2);
  init_h<<<(B_ * KA) / 256, 256, 0, stream>>>(h, hb);

  // Phase 1: gates_x = bf16( x @ W_i^T + b )   [6144 x 7200]
  gemm_nt<<<dim3(48, 57, 1), 256, 0, stream>>>(
      xb, EP, Wi, EP, N3, nullptr, gx, N3, 0, bias, EP, EP, 1 << 30);

  // Phase 2: 48 sequential GRU steps.
  // G = A'(128x7200) @ B'^T, A'=[h_hi|h_lo|h_hi], B'=[W_hi|W_hi|W_lo] via bkwrap.
  for (int t = 0; t < S_; ++t) {
    gemm_nt<<<dim3(1, 57, ZSPLIT), 256, 0, stream>>>(
        hb, KA, W2, 4800, N3, Gp, nullptr, N3, (long)B_ * N3,
        nullptr, KA, KCHUNK, KH);
    gate_step<<<(B_ * H_) / 256, 256, 0, stream>>>(Gp, gx, h, hb, lengths, out, t);
  }
}

// Round 4
// 2317.374 us; speedup vs baseline: 1.1888x; 1.1888x over previous
//
#include <hip/hip_runtime.h>
#include <stdint.h>
#include <stddef.h>

// Problem dims
#define B_  128
#define S_  48
#define E_  620
#define EP  640    // E padded to multiple of 32 (zeros)
#define H_  2400
#define N3  7200   // 3*H (r,i,n concatenated)
#define KH  2400
#define KA  7200   // logical K for recurrent GEMM: [h_hi | h_lo | h_hi]
#define ZSPLIT 6
#define KCHUNK 1216  // 38*32; 6*1216 = 7296 >= 7200

typedef __attribute__((ext_vector_type(8))) short   short8;
typedef __attribute__((ext_vector_type(8))) __bf16  bf16x8;
typedef __attribute__((ext_vector_type(4))) float   floatx4;

__device__ __forceinline__ short f2bf(float f) {
  union { float f; uint32_t u; } v; v.f = f;
  return (short)((v.u + 0x7fffu + ((v.u >> 16) & 1u)) >> 16);  // RNE
}
__device__ __forceinline__ float bf2f(short s) {
  union { uint32_t u; float f; } v; v.u = ((uint32_t)(uint16_t)s) << 16;
  return v.f;
}

// ---- x = bf16(emb[tokens]), padded [6144, 640] ----
__global__ void gather_cast_x(const int* __restrict__ tokens,
                              const float* __restrict__ emb,
                              short* __restrict__ xb) {
  int idx = blockIdx.x * 256 + threadIdx.x;       // over 6144*EP
  int m = idx / EP, c = idx - m * EP;
  float v = 0.f;
  if (c < E_) v = emb[(size_t)tokens[m] * E_ + c];
  xb[idx] = f2bf(v);
}

// ---- W_i = bf16 concat(W_ir,W_ii,W_in) [7200, 640]; bias concat [7200] ----
__global__ void convert_wi(const float* __restrict__ Wir, const float* __restrict__ Wii,
                           const float* __restrict__ Win,
                           const float* __restrict__ bir, const float* __restrict__ bii,
                           const float* __restrict__ bin,
                           short* __restrict__ Wi, float* __restrict__ bias) {
  int idx = blockIdx.x * 256 + threadIdx.x;       // over N3*EP
  int r = idx / EP, c = idx - r * EP;
  const float* W = (r < H_) ? Wir : (r < 2*H_ ? Wii : Win);
  int rr = (r < H_) ? r : (r < 2*H_ ? r - H_ : r - 2*H_);
  float v = (c < E_) ? W[(size_t)rr * E_ + c] : 0.f;
  Wi[idx] = f2bf(v);
  if (c == 0) {
    const float* bb = (r < H_) ? bir : (r < 2*H_ ? bii : bin);
    bias[r] = bb[rr];
  }
}

// ---- W2 = [W_hi | W_lo] of concat(W_hr,W_hi,W_hn): [7200, 4800] bf16 ----
__global__ void convert_wh(const float* __restrict__ Whr, const float* __restrict__ Whi,
                           const float* __restrict__ Whn, short* __restrict__ W2) {
  int idx = blockIdx.x * 256 + threadIdx.x;       // over N3*KH
  int r = idx / KH, c = idx - r * KH;
  const float* W = (r < H_) ? Whr : (r < 2*H_ ? Whi : Whn);
  int rr = (r < H_) ? r : (r < 2*H_ ? r - H_ : r - 2*H_);
  float w = W[(size_t)rr * KH + c];
  short hi = f2bf(w);
  short lo = f2bf(w - bf2f(hi));
  W2[(size_t)r * 4800 + c] = hi;
  W2[(size_t)r * 4800 + KH + c] = lo;
}

__global__ void init_h(float* __restrict__ h, short* __restrict__ hb) {
  int idx = blockIdx.x * 256 + threadIdx.x;       // over B_*KA
  hb[idx] = 0;
  if (idx < B_ * H_) h[idx] = 0.f;
}

// ---- Generic NT bf16 GEMM: C[m,n] = sum_k A[m,k]*B[n,k] (+bias[n]) ----
// Tile M=128 x N=64 x BK=32. 256 threads = 4 waves, wave-tile 64x32.
// Fragment-major LDS (16B chunk c = frag*64 + q*16 + fm): ds_write and
// ds_read are both lane-contiguous -> 0 bank conflicts (verified r3).
// Staging is VGPR-mediated with explicit next-tile prefetch issued BEFORE
// the MFMA body -> global latency overlaps compute (r3's global_load_lds
// serialized on the vmcnt(0)+barrier drain every iter).
// grid.z = K-split (kchunk); f32 partials to Cf + z*czstride, OR bf16 to Cb.
// bkwrap: B k-index = (k < bkwrap ? k : k - bkwrap) -> realizes
// B' = [W_hi | W_hi | W_lo] over stored [W_hi | W_lo].
__global__ __launch_bounds__(256) void gemm_nt(
    const short* __restrict__ A, int lda,
    const short* __restrict__ Bm, int ldb, int N,
    float* __restrict__ Cf, short* __restrict__ Cb, int ldc, long czstride,
    const float* __restrict__ bias, int K, int kchunk, int bkwrap)
{
  __shared__ short As[4096];   // 512 x 16B chunks: 128 m-rows x 32 k
  __shared__ short Bs[2048];   // 256 x 16B chunks:  64 n-rows x 32 k

  const int tid = threadIdx.x;
  const int m0 = blockIdx.x * 128;
  const int n0 = blockIdx.y * 64;
  const int z  = blockIdx.z;
  const int kb = z * kchunk;
  const int ke = min(K, kb + kchunk);

  const int lane = tid & 63;
  const int w  = tid >> 6;
  const int wm = (w & 1) * 64;     // wave m-offset
  const int wn = (w >> 1) * 32;    // wave n-offset

  // staging descriptors: chunk c -> row = (c>>6)*16 + (c&15), kcol = ((c>>4)&3)*8
  const int c0 = tid, c1 = tid + 256;
  const int rA0 = m0 + (c0 >> 6) * 16 + (c0 & 15), qA0 = ((c0 >> 4) & 3) * 8;
  const int rA1 = m0 + (c1 >> 6) * 16 + (c1 & 15), qA1 = ((c1 >> 4) & 3) * 8;
  int rB = n0 + (tid >> 6) * 16 + (tid & 15); if (rB >= N) rB = N - 1;
  const int qB = ((tid >> 4) & 3) * 8;

  floatx4 acc[4][2] = {};

  // prefetch k-tile 0 into VGPRs
  int bk0 = (kb < bkwrap) ? kb : kb - bkwrap;
  short8 ga0 = *(const short8*)(A  + (size_t)rA0 * lda + kb  + qA0);
  short8 ga1 = *(const short8*)(A  + (size_t)rA1 * lda + kb  + qA1);
  short8 gb  = *(const short8*)(Bm + (size_t)rB  * ldb + bk0 + qB);

  for (int k0 = kb; k0 < ke; k0 += 32) {
    __syncthreads();                    // LDS free (prev iter's reads done)
    *(short8*)(As + c0 * 8)  = ga0;
    *(short8*)(As + c1 * 8)  = ga1;
    *(short8*)(Bs + tid * 8) = gb;
    __syncthreads();

    int kn = k0 + 32;
    if (kn < ke) {                      // prefetch next tile: overlaps MFMAs
      int bkn = (kn < bkwrap) ? kn : kn - bkwrap;
      ga0 = *(const short8*)(A  + (size_t)rA0 * lda + kn  + qA0);
      ga1 = *(const short8*)(A  + (size_t)rA1 * lda + kn  + qA1);
      gb  = *(const short8*)(Bm + (size_t)rB  * ldb + bkn + qB);
    }

    bf16x8 a[4], b[2];
    #pragma unroll
    for (int i = 0; i < 4; ++i)
      a[i] = __builtin_bit_cast(bf16x8,
               *(const short8*)(As + (((wm >> 4) + i) * 64 + lane) * 8));
    #pragma unroll
    for (int i = 0; i < 2; ++i)
      b[i] = __builtin_bit_cast(bf16x8,
               *(const short8*)(Bs + (((wn >> 4) + i) * 64 + lane) * 8));
    #pragma unroll
    for (int mf = 0; mf < 4; ++mf)
      #pragma unroll
      for (int nf = 0; nf < 2; ++nf)
        acc[mf][nf] = __builtin_amdgcn_mfma_f32_16x16x32_bf16(
            a[mf], b[nf], acc[mf][nf], 0, 0, 0);
  }

  // C/D layout (m89-verified): col = lane&15, row = (lane>>4)*4 + reg
  const int col = lane & 15;
  const int qr = (lane >> 4) * 4;
  #pragma unroll
  for (int nf = 0; nf < 2; ++nf) {
    int n = n0 + wn + nf * 16 + col;
    if (n >= N) continue;
    float bv = bias ? bias[n] : 0.f;
    #pragma unroll
    for (int mf = 0; mf < 4; ++mf) {
      #pragma unroll
      for (int r = 0; r < 4; ++r) {
        int m = m0 + wm + mf * 16 + qr + r;
        float v = acc[mf][nf][r] + bv;
        if (Cf) Cf[(size_t)z * czstride + (size_t)m * ldc + n] = v;
        else    Cb[(size_t)m * ldc + n] = f2bf(v);
      }
    }
  }
}

// ---- GRU gate update for step t; h kept f32, A' = [h_hi|h_lo|h_hi] bf16 ----
__global__ void gate_step(const float* __restrict__ Gp, const short* __restrict__ gx,
                          float* __restrict__ h, short* __restrict__ hb,
                          const int* __restrict__ lengths, float* __restrict__ out,
                          int t)
{
  int idx = blockIdx.x * 256 + threadIdx.x;   // over B_*H_
  int b = idx / H_;
  int j = idx - b * H_;

  size_t rx = ((size_t)b * S_ + t) * N3;
  float xr = bf2f(gx[rx + j]);
  float xi = bf2f(gx[rx + H_ + j]);
  float xn = bf2f(gx[rx + 2 * H_ + j]);

  size_t gi = (size_t)b * N3;
  float Gr = 0.f, Gi = 0.f, Gn = 0.f;
  #pragma unroll
  for (int z = 0; z < ZSPLIT; ++z) {
    const float* Gz = Gp + (size_t)z * B_ * N3 + gi;
    Gr += Gz[j]; Gi += Gz[H_ + j]; Gn += Gz[2 * H_ + j];
  }

  float ho = h[idx];
  float r  = 1.f / (1.f + __expf(-(xr + Gr)));
  float ig = 1.f / (1.f + __expf(-(xi + Gi)));
  float n  = tanhf(xn + r * Gn);
  float hn = (1.f - ig) * n + ig * ho;

  h[idx] = hn;
  short hi16 = f2bf(hn);
  short lo16 = f2bf(hn - bf2f(hi16));
  size_t ra = (size_t)b * KA;
  hb[ra + j]            = hi16;
  hb[ra + H_ + j]       = lo16;
  hb[ra + 2 * H_ + j]   = hi16;

  int lc = lengths[b] - 1;
  lc = lc < 0 ? 0 : (lc > S_ - 1 ? S_ - 1 : lc);
  if (t == lc) out[idx] = hn;
}

extern "C" void kernel_launch(void* const* d_in, const int* in_sizes, int n_in,
                              void* d_out, int out_size, void* d_ws, size_t ws_size,
                              hipStream_t stream)
{
  const int*   tokens  = (const int*)d_in[0];
  const int*   lengths = (const int*)d_in[1];
  const float* emb = (const float*)d_in[2];
  const float* Wir = (const float*)d_in[3];
  const float* Wii = (const float*)d_in[4];
  const float* Win = (const float*)d_in[5];
  const float* bir = (const float*)d_in[6];
  const float* bii = (const float*)d_in[7];
  const float* bin = (const float*)d_in[8];
  const float* Whr = (const float*)d_in[9];
  const float* Whi = (const float*)d_in[10];
  const float* Whn = (const float*)d_in[11];
  float* out = (float*)d_out;

  char* ws = (char*)d_ws;
  size_t off = 0;
  auto alloc = [&](size_t bytes) {
    void* p = ws + off;
    off = (off + bytes + 255) & ~(size_t)255;
    return p;
  };
  short* xb   = (short*)alloc((size_t)(B_ * S_) * EP * 2);     //  7.9 MB
  short* Wi   = (short*)alloc((size_t)N3 * EP * 2);            //  9.2 MB
  short* W2   = (short*)alloc((size_t)N3 * 4800 * 2);          // 69.1 MB [W_hi|W_lo]
  float* bias = (float*)alloc((size_t)N3 * 4);
  short* gx   = (short*)alloc((size_t)(B_ * S_) * N3 * 2);     // 88.5 MB
  float* Gp   = (float*)alloc((size_t)ZSPLIT * B_ * N3 * 4);   // 22.1 MB
  float* h    = (float*)alloc((size_t)B_ * H_ * 4);
  short* hb   = (short*)alloc((size_t)B_ * KA * 2);            //  1.8 MB

  // conversions / gather (independent, cheap)
  gather_cast_x<<<(B_ * S_ * EP) / 256, 256, 0, stream>>>(tokens, emb, xb);
  convert_wi<<<(N3 * EP) / 256, 256, 0, stream>>>(Wir, Wii, Win, bir, bii, bin, Wi, bias);
  convert_wh<<<(N3 * KH) / 256, 256, 0, stream>>>(Whr, Whi, Whn, W2);
  init_h<<<(B_ * KA) / 256, 256, 0, stream>>>(h, hb);

  // Phase 1: gates_x = bf16( x @ W_i^T + b )   [6144 x 7200], N-tiles of 64
  gemm_nt<<<dim3(48, 113, 1), 256, 0, stream>>>(
      xb, EP, Wi, EP, N3, nullptr, gx, N3, 0, bias, EP, EP, 1 << 30);

  // Phase 2: 48 sequential GRU steps.
  // G = A'(128x7200) @ B'^T, A'=[h_hi|h_lo|h_hi], B'=[W_hi|W_hi|W_lo] via bkwrap.
  // Grid 113 x 6 = 678 blocks (~2.7/CU) for cross-block latency overlap.
  for (int t = 0; t < S_; ++t) {
    gemm_nt<<<dim3(1, 113, ZSPLIT), 256, 0, stream>>>(
        hb, KA, W2, 4800, N3, Gp, nullptr, N3, (long)B_ * N3,
        nullptr, KA, KCHUNK, KH);
    gate_step<<<(B_ * H_) / 256, 256, 0, stream>>>(Gp, gx, h, hb, lengths, out, t);
  }
}

// Round 5
// 2290.647 us; speedup vs baseline: 1.2027x; 1.0117x over previous
//
#include <hip/hip_runtime.h>
#include <stdint.h>
#include <stddef.h>

// Problem dims
#define B_  128
#define S_  48
#define E_  620
#define EP  640    // E padded to multiple of 32 (zeros)
#define H_  2400
#define N3  7200   // 3*H (r,i,n concatenated)
#define KH  2400
#define KA  7200   // logical K for recurrent GEMM: [h_hi | h_lo | h_hi]
#define ZSPLIT 9   // phase-2 k-split: 9 chunks x 800 (25 iters of 32, exact)
#define P2_ITERS 25
#define P1_ITERS 20  // phase-1 K = 640 = 20 x 32

typedef __attribute__((ext_vector_type(8))) short   short8;
typedef __attribute__((ext_vector_type(8))) __bf16  bf16x8;
typedef __attribute__((ext_vector_type(4))) float   floatx4;

__device__ __forceinline__ short f2bf(float f) {
  union { float f; uint32_t u; } v; v.f = f;
  return (short)((v.u + 0x7fffu + ((v.u >> 16) & 1u)) >> 16);  // RNE
}
__device__ __forceinline__ float bf2f(short s) {
  union { uint32_t u; float f; } v; v.u = ((uint32_t)(uint16_t)s) << 16;
  return v.f;
}
__device__ __forceinline__ bf16x8 bcast(short8 s) {
  return __builtin_bit_cast(bf16x8, s);
}

// Workgroup barrier that waits ONLY on LDS ops (lgkmcnt(0)); in-flight global
// loads keep flying across it. 0xC07F = vmcnt(63) expcnt(7) lgkmcnt(0).
// sched_barrier(0) pins LDS reads/writes on their side of the barrier
// (s_barrier alone is not a memory fence for the scheduler).
__device__ __forceinline__ void lds_barrier() {
  __builtin_amdgcn_sched_barrier(0);
  __builtin_amdgcn_s_waitcnt(0xC07F);
  __builtin_amdgcn_s_barrier();
  __builtin_amdgcn_sched_barrier(0);
}

// ---- x = bf16(emb[tokens]), padded [6144, 640] ----
__global__ void gather_cast_x(const int* __restrict__ tokens,
                              const float* __restrict__ emb,
                              short* __restrict__ xb) {
  int idx = blockIdx.x * 256 + threadIdx.x;       // over 6144*EP
  int m = idx / EP, c = idx - m * EP;
  float v = 0.f;
  if (c < E_) v = emb[(size_t)tokens[m] * E_ + c];
  xb[idx] = f2bf(v);
}

// ---- W_i = bf16 concat(W_ir,W_ii,W_in) [7200, 640]; bias concat [7200] ----
__global__ void convert_wi(const float* __restrict__ Wir, const float* __restrict__ Wii,
                           const float* __restrict__ Win,
                           const float* __restrict__ bir, const float* __restrict__ bii,
                           const float* __restrict__ bin,
                           short* __restrict__ Wi, float* __restrict__ bias) {
  int idx = blockIdx.x * 256 + threadIdx.x;       // over N3*EP
  int r = idx / EP, c = idx - r * EP;
  const float* W = (r < H_) ? Wir : (r < 2*H_ ? Wii : Win);
  int rr = (r < H_) ? r : (r < 2*H_ ? r - H_ : r - 2*H_);
  float v = (c < E_) ? W[(size_t)rr * E_ + c] : 0.f;
  Wi[idx] = f2bf(v);
  if (c == 0) {
    const float* bb = (r < H_) ? bir : (r < 2*H_ ? bii : bin);
    bias[r] = bb[rr];
  }
}

// ---- W2 = [W_hi | W_lo] of concat(W_hr,W_hi,W_hn): [7200, 4800] bf16 ----
__global__ void convert_wh(const float* __restrict__ Whr, const float* __restrict__ Whi,
                           const float* __restrict__ Whn, short* __restrict__ W2) {
  int idx = blockIdx.x * 256 + threadIdx.x;       // over N3*KH
  int r = idx / KH, c = idx - r * KH;
  const float* W = (r < H_) ? Whr : (r < 2*H_ ? Whi : Whn);
  int rr = (r < H_) ? r : (r < 2*H_ ? r - H_ : r - 2*H_);
  float w = W[(size_t)rr * KH + c];
  short hi = f2bf(w);
  short lo = f2bf(w - bf2f(hi));
  W2[(size_t)r * 4800 + c] = hi;
  W2[(size_t)r * 4800 + KH + c] = lo;
}

__global__ void init_h(float* __restrict__ h, short* __restrict__ hb) {
  int idx = blockIdx.x * 256 + threadIdx.x;       // over B_*KA
  hb[idx] = 0;
  if (idx < B_ * H_) h[idx] = 0.f;
}

// ---- Phase 1: gx = bf16( xb @ Wi^T + bias )  [6144 x 7200], K=640 ----
// 128x128 tile, 4 waves (64x64 each), fragment-major LDS double-buffered,
// VGPR prefetch depth 2, lgkm-only barrier (1 per k-iter).
__global__ __launch_bounds__(256, 2) void gemm_x(
    const short* __restrict__ A,   // xb [6144 x 640]
    const short* __restrict__ Bm,  // Wi [7200 x 640]
    short* __restrict__ C,         // gx [6144 x 7200]
    const float* __restrict__ bias)
{
  __shared__ short As[2][4096];   // 8 KB buffers: 128 rows x 32 k, frag-major
  __shared__ short Bs[2][4096];

  const int tid = threadIdx.x;
  const int lane = tid & 63;
  const int w = tid >> 6;
  const int m0 = blockIdx.x * 128;
  const int n0 = blockIdx.y * 128;
  const int wm = (w >> 1) * 64, wn = (w & 1) * 64;

  // staging: chunk c -> row (c>>6)*16 + (c&15), kcol ((c>>4)&3)*8
  const int c0 = tid, c1 = tid + 256;
  const int rA0 = m0 + (c0 >> 6) * 16 + (c0 & 15), q0 = ((c0 >> 4) & 3) * 8;
  const int rA1 = m0 + (c1 >> 6) * 16 + (c1 & 15), q1 = ((c1 >> 4) & 3) * 8;
  int rB0 = n0 + (c0 >> 6) * 16 + (c0 & 15); if (rB0 >= N3) rB0 = N3 - 1;
  int rB1 = n0 + (c1 >> 6) * 16 + (c1 & 15); if (rB1 >= N3) rB1 = N3 - 1;
  const short* pA0 = A  + (size_t)rA0 * EP + q0;
  const short* pA1 = A  + (size_t)rA1 * EP + q1;
  const short* pB0 = Bm + (size_t)rB0 * EP + q0;
  const short* pB1 = Bm + (size_t)rB1 * EP + q1;

  floatx4 acc[4][4] = {};

  short8 ga0 = *(const short8*)(pA0);
  short8 ga1 = *(const short8*)(pA1);
  short8 gb0 = *(const short8*)(pB0);
  short8 gb1 = *(const short8*)(pB1);
  *(short8*)(As[0] + c0 * 8) = ga0;
  *(short8*)(As[0] + c1 * 8) = ga1;
  *(short8*)(Bs[0] + c0 * 8) = gb0;
  *(short8*)(Bs[0] + c1 * 8) = gb1;
  ga0 = *(const short8*)(pA0 + 32);
  ga1 = *(const short8*)(pA1 + 32);
  gb0 = *(const short8*)(pB0 + 32);
  gb1 = *(const short8*)(pB1 + 32);
  lds_barrier();

  #pragma unroll
  for (int i = 0; i < P1_ITERS; ++i) {
    const int cur = i & 1, nxt = cur ^ 1;
    bf16x8 a[4], b[4];
    #pragma unroll
    for (int f = 0; f < 4; ++f) {
      a[f] = bcast(*(const short8*)(As[cur] + (((wm >> 4) + f) * 64 + lane) * 8));
      b[f] = bcast(*(const short8*)(Bs[cur] + (((wn >> 4) + f) * 64 + lane) * 8));
    }
    if (i + 1 < P1_ITERS) {          // stage tile i+1 (regs, loaded iter i-1)
      *(short8*)(As[nxt] + c0 * 8) = ga0;
      *(short8*)(As[nxt] + c1 * 8) = ga1;
      *(short8*)(Bs[nxt] + c0 * 8) = gb0;
      *(short8*)(Bs[nxt] + c1 * 8) = gb1;
    }
    if (i + 2 < P1_ITERS) {          // prefetch tile i+2 (flies across barrier)
      int ko = (i + 2) * 32;
      ga0 = *(const short8*)(pA0 + ko);
      ga1 = *(const short8*)(pA1 + ko);
      gb0 = *(const short8*)(pB0 + ko);
      gb1 = *(const short8*)(pB1 + ko);
    }
    #pragma unroll
    for (int mf = 0; mf < 4; ++mf)
      #pragma unroll
      for (int nf = 0; nf < 4; ++nf)
        acc[mf][nf] = __builtin_amdgcn_mfma_f32_16x16x32_bf16(
            a[mf], b[nf], acc[mf][nf], 0, 0, 0);
    if (i + 1 < P1_ITERS) lds_barrier();
  }

  // C/D layout: col = lane&15 -> n, row = (lane>>4)*4 + reg -> m
  const int col = lane & 15, qr = (lane >> 4) * 4;
  #pragma unroll
  for (int nf = 0; nf < 4; ++nf) {
    int n = n0 + wn + nf * 16 + col;
    if (n >= N3) continue;
    float bv = bias[n];
    #pragma unroll
    for (int mf = 0; mf < 4; ++mf)
      #pragma unroll
      for (int r = 0; r < 4; ++r)
        C[(size_t)(m0 + wm + mf * 16 + qr + r) * N3 + n] =
            f2bf(acc[mf][nf][r] + bv);
  }
}

// ---- Phase 2: Gp[z] = hb(128 x 800-chunk) @ W'^T  -> f32 partials ----
// Block = 4 waves; wave-tile M=128 x N=32 (acc 8x2). A (h) staged in LDS
// (8 KB dbuf, shared by 4 waves); B (weights, the 105 MB/step stream) loads
// DIRECTLY global->VGPR fragments through a depth-4 ring - no barrier ever
// blocks it. grid = (57 n-blocks, 9 k-chunks); chunk c covers k in
// [800c, 800c+800); wrap: W2 col = k - (c<3 ? 0 : 2400) (never straddles).
__global__ __launch_bounds__(256, 2) void gemm_h(
    const short* __restrict__ Ah,  // hb [128 x 7200]
    const short* __restrict__ W2,  // [7200 x 4800] = [W_hi | W_lo]
    float* __restrict__ Gp)        // [ZSPLIT][128][7200]
{
  __shared__ short As[2][4096];

  const int tid = threadIdx.x;
  const int lane = tid & 63;
  const int w = tid >> 6;
  const int n0 = blockIdx.x * 128;
  const int z  = blockIdx.y;
  const int kb = z * 800;
  const int koff = (z < 3) ? 0 : 2400;
  const int wn = w * 32;

  const int c0 = tid, c1 = tid + 256;
  const int rA0 = (c0 >> 6) * 16 + (c0 & 15), q0 = ((c0 >> 4) & 3) * 8;
  const int rA1 = (c1 >> 6) * 16 + (c1 & 15), q1 = ((c1 >> 4) & 3) * 8;
  const short* pA0 = Ah + (size_t)rA0 * KA + kb + q0;
  const short* pA1 = Ah + (size_t)rA1 * KA + kb + q1;

  int rB0 = n0 + wn + (lane & 15);      if (rB0 >= N3) rB0 = N3 - 1;
  int rB1 = n0 + wn + 16 + (lane & 15); if (rB1 >= N3) rB1 = N3 - 1;
  const int qB = (lane >> 4) * 8;
  const short* pB0 = W2 + (size_t)rB0 * 4800 + (kb - koff) + qB;
  const short* pB1 = W2 + (size_t)rB1 * 4800 + (kb - koff) + qB;

  floatx4 acc[8][2] = {};   // 64 VGPRs

  short8 ga0 = *(const short8*)(pA0);
  short8 ga1 = *(const short8*)(pA1);
  *(short8*)(As[0] + c0 * 8) = ga0;
  *(short8*)(As[0] + c1 * 8) = ga1;
  ga0 = *(const short8*)(pA0 + 32);
  ga1 = *(const short8*)(pA1 + 32);
  short8 pb[4][2];
  #pragma unroll
  for (int d = 0; d < 4; ++d) {
    pb[d][0] = *(const short8*)(pB0 + d * 32);
    pb[d][1] = *(const short8*)(pB1 + d * 32);
  }
  lds_barrier();

  #pragma unroll
  for (int i = 0; i < P2_ITERS; ++i) {
    const int cur = i & 1, nxt = cur ^ 1;
    bf16x8 b0 = bcast(pb[i & 3][0]);
    bf16x8 b1 = bcast(pb[i & 3][1]);
    bf16x8 a[8];
    #pragma unroll
    for (int f = 0; f < 8; ++f)
      a[f] = bcast(*(const short8*)(As[cur] + (f * 64 + lane) * 8));
    if (i + 1 < P2_ITERS) {
      *(short8*)(As[nxt] + c0 * 8) = ga0;
      *(short8*)(As[nxt] + c1 * 8) = ga1;
    }
    if (i + 2 < P2_ITERS) {
      ga0 = *(const short8*)(pA0 + (i + 2) * 32);
      ga1 = *(const short8*)(pA1 + (i + 2) * 32);
    }
    if (i + 4 < P2_ITERS) {          // refill ring slot just consumed
      pb[i & 3][0] = *(const short8*)(pB0 + (i + 4) * 32);
      pb[i & 3][1] = *(const short8*)(pB1 + (i + 4) * 32);
    }
    #pragma unroll
    for (int mf = 0; mf < 8; ++mf) {
      acc[mf][0] = __builtin_amdgcn_mfma_f32_16x16x32_bf16(a[mf], b0, acc[mf][0], 0, 0, 0);
      acc[mf][1] = __builtin_amdgcn_mfma_f32_16x16x32_bf16(a[mf], b1, acc[mf][1], 0, 0, 0);
    }
    if (i + 1 < P2_ITERS) lds_barrier();
  }

  const int col = lane & 15, qr = (lane >> 4) * 4;
  float* G = Gp + (size_t)z * (B_ * N3);
  #pragma unroll
  for (int nf = 0; nf < 2; ++nf) {
    int n = n0 + wn + nf * 16 + col;
    if (n >= N3) continue;
    #pragma unroll
    for (int mf = 0; mf < 8; ++mf)
      #pragma unroll
      for (int r = 0; r < 4; ++r)
        G[(size_t)(mf * 16 + qr + r) * N3 + n] = acc[mf][nf][r];
  }
}

// ---- GRU gate update for step t; h kept f32, A' = [h_hi|h_lo|h_hi] bf16 ----
__global__ void gate_step(const float* __restrict__ Gp, const short* __restrict__ gx,
                          float* __restrict__ h, short* __restrict__ hb,
                          const int* __restrict__ lengths, float* __restrict__ out,
                          int t)
{
  int idx = blockIdx.x * 256 + threadIdx.x;   // over B_*H_
  int b = idx / H_;
  int j = idx - b * H_;

  size_t rx = ((size_t)b * S_ + t) * N3;
  float xr = bf2f(gx[rx + j]);
  float xi = bf2f(gx[rx + H_ + j]);
  float xn = bf2f(gx[rx + 2 * H_ + j]);

  size_t gi = (size_t)b * N3;
  float Gr = 0.f, Gi = 0.f, Gn = 0.f;
  #pragma unroll
  for (int z = 0; z < ZSPLIT; ++z) {
    const float* Gz = Gp + (size_t)z * B_ * N3 + gi;
    Gr += Gz[j]; Gi += Gz[H_ + j]; Gn += Gz[2 * H_ + j];
  }

  float ho = h[idx];
  float r  = 1.f / (1.f + __expf(-(xr + Gr)));
  float ig = 1.f / (1.f + __expf(-(xi + Gi)));
  float n  = tanhf(xn + r * Gn);
  float hn = (1.f - ig) * n + ig * ho;

  h[idx] = hn;
  short hi16 = f2bf(hn);
  short lo16 = f2bf(hn - bf2f(hi16));
  size_t ra = (size_t)b * KA;
  hb[ra + j]            = hi16;
  hb[ra + H_ + j]       = lo16;
  hb[ra + 2 * H_ + j]   = hi16;

  int lc = lengths[b] - 1;
  lc = lc < 0 ? 0 : (lc > S_ - 1 ? S_ - 1 : lc);
  if (t == lc) out[idx] = hn;
}

extern "C" void kernel_launch(void* const* d_in, const int* in_sizes, int n_in,
                              void* d_out, int out_size, void* d_ws, size_t ws_size,
                              hipStream_t stream)
{
  const int*   tokens  = (const int*)d_in[0];
  const int*   lengths = (const int*)d_in[1];
  const float* emb = (const float*)d_in[2];
  const float* Wir = (const float*)d_in[3];
  const float* Wii = (const float*)d_in[4];
  const float* Win = (const float*)d_in[5];
  const float* bir = (const float*)d_in[6];
  const float* bii = (const float*)d_in[7];
  const float* bin = (const float*)d_in[8];
  const float* Whr = (const float*)d_in[9];
  const float* Whi = (const float*)d_in[10];
  const float* Whn = (const float*)d_in[11];
  float* out = (float*)d_out;

  char* ws = (char*)d_ws;
  size_t off = 0;
  auto alloc = [&](size_t bytes) {
    void* p = ws + off;
    off = (off + bytes + 255) & ~(size_t)255;
    return p;
  };
  short* xb   = (short*)alloc((size_t)(B_ * S_) * EP * 2);     //  7.9 MB
  short* Wi   = (short*)alloc((size_t)N3 * EP * 2);            //  9.2 MB
  short* W2   = (short*)alloc((size_t)N3 * 4800 * 2);          // 69.1 MB [W_hi|W_lo]
  float* bias = (float*)alloc((size_t)N3 * 4);
  short* gx   = (short*)alloc((size_t)(B_ * S_) * N3 * 2);     // 88.5 MB
  float* Gp   = (float*)alloc((size_t)ZSPLIT * B_ * N3 * 4);   // 33.2 MB
  float* h    = (float*)alloc((size_t)B_ * H_ * 4);
  short* hb   = (short*)alloc((size_t)B_ * KA * 2);            //  1.8 MB

  // conversions / gather (independent, cheap)
  gather_cast_x<<<(B_ * S_ * EP) / 256, 256, 0, stream>>>(tokens, emb, xb);
  convert_wi<<<(N3 * EP) / 256, 256, 0, stream>>>(Wir, Wii, Win, bir, bii, bin, Wi, bias);
  convert_wh<<<(N3 * KH) / 256, 256, 0, stream>>>(Whr, Whi, Whn, W2);
  init_h<<<(B_ * KA) / 256, 256, 0, stream>>>(h, hb);

  // Phase 1: gates_x = bf16( x @ W_i^T + b )   [6144 x 7200]
  gemm_x<<<dim3(48, 57), 256, 0, stream>>>(xb, Wi, gx, bias);

  // Phase 2: 48 sequential GRU steps.
  for (int t = 0; t < S_; ++t) {
    gemm_h<<<dim3(57, ZSPLIT), 256, 0, stream>>>(hb, W2, Gp);
    gate_step<<<(B_ * H_) / 256, 256, 0, stream>>>(Gp, gx, h, hb, lengths, out, t);
  }
}